// Round 10
// baseline (396.025 us; speedup 1.0000x reference)
//
#include <hip/hip_runtime.h>

// MiniRocket on MI355X — round 10: adaptive (GK, FS) per dilation class.
// r9 measured: 315 us, VGPR 60, no spill, VALUBusy 74% -> op-count-bound.
// This round removes the two instance redundancies: (1) bias-split recompute
// for F>4 dilations (di 0,1,3 recomputed taps+sum+cv 5x/3x/2x), (2) small
// GK amortization. One pass per dilation with full-F counters:
//   A: di0  F=19 GK=3  (28 groups)   B: di1 F=12 GK=4 (21)
//   C: di3  F=8  GK=6  (14)          D: F=4 GK=12 (7)   E: F=3 GK=12 (7)
// Static op model: 40K -> 30K lane-ops/(t,n), predict ~235-255 us mr_main.
// Proven-and-kept: zero-padded xTp (no bounds checks), 256-thr blocks,
// blockIdx-only selectors (biases -> SGPRs), unroll-1 t-loops, single-base
// addressing xb[(t+j*d)*NS] (no pointer arrays).
//
// ws layout: [0, 2MB) xTp ; [2MB, +9.77MB) outT. Total ~12.3 MB.

namespace {

constexpr int LSER = 1024;
constexpr int NS   = 256;
constexpr int NFEAT = 9996;
constexpr int NDIL = 25;
constexpr int TCH  = 64;             // t per work item (16 slices)
constexpr int NBLK = 3472;
constexpr int PADROWS = 2048;        // padded rows: data at [512, 1536)
constexpr int ROW0 = 512;

__constant__ int c_DIL[NDIL] = {1,2,3,4,5,6,7,8,10,12,14,16,19,22,26,31,36,42,50,58,68,79,93,109,127};
__constant__ int c_F[NDIL]   = {19,12,4,8,4,4,4,4,4,4,4,4,4,4,4,4,4,3,3,3,3,3,3,3,3};
__constant__ int c_FOFF[NDIL + 1] = {
    0,1596,2604,2940,3612,3948,4284,4620,4956,5292,5628,5964,6300,6636,6972,
    7308,7644,7980,8232,8484,8736,8988,9240,9492,9744,9996};
// blocks per dilation = groups*16: A 448, B 336, C 224, D/E 112
__constant__ int c_BSTART[NDIL + 1] = {
    0,448,784,896,1120,1232,1344,1456,1568,1680,1792,1904,2016,2128,2240,
    2352,2464,2576,2688,2800,2912,3024,3136,3248,3360,3472};

constexpr int CIDX[84][3] = {
    {0,1,2},{0,1,3},{0,1,4},{0,1,5},{0,1,6},{0,1,7},{0,1,8},
    {0,2,3},{0,2,4},{0,2,5},{0,2,6},{0,2,7},{0,2,8},
    {0,3,4},{0,3,5},{0,3,6},{0,3,7},{0,3,8},
    {0,4,5},{0,4,6},{0,4,7},{0,4,8},
    {0,5,6},{0,5,7},{0,5,8},
    {0,6,7},{0,6,8},
    {0,7,8},
    {1,2,3},{1,2,4},{1,2,5},{1,2,6},{1,2,7},{1,2,8},
    {1,3,4},{1,3,5},{1,3,6},{1,3,7},{1,3,8},
    {1,4,5},{1,4,6},{1,4,7},{1,4,8},
    {1,5,6},{1,5,7},{1,5,8},
    {1,6,7},{1,6,8},
    {1,7,8},
    {2,3,4},{2,3,5},{2,3,6},{2,3,7},{2,3,8},
    {2,4,5},{2,4,6},{2,4,7},{2,4,8},
    {2,5,6},{2,5,7},{2,5,8},
    {2,6,7},{2,6,8},
    {2,7,8},
    {3,4,5},{3,4,6},{3,4,7},{3,4,8},
    {3,5,6},{3,5,7},{3,5,8},
    {3,6,7},{3,6,8},
    {3,7,8},
    {4,5,6},{4,5,7},{4,5,8},
    {4,6,7},{4,6,8},
    {4,7,8},
    {5,6,7},{5,6,8},
    {5,7,8},
    {6,7,8}};

__device__ __forceinline__ int imin(int a, int b) { return a < b ? a : b; }
__device__ __forceinline__ int imax(int a, int b) { return a > b ? a : b; }

// PSEL < 0: all kernels. PSEL 0/1: kernels with (K0+KK)&1 == PSEL (padded parity).
template <int GK, int K0, int FS, int PSEL, int KK>
__device__ __forceinline__ void do_kernels(const float (&s)[9], float sum,
                                           const float (&bv)[GK][FS],
                                           unsigned (&cnt)[GK][FS]) {
  if constexpr (KK < GK) {
    if constexpr (PSEL < 0 || (((K0 + KK) & 1) == PSEL)) {
      constexpr int ia = CIDX[K0 + KK][0];
      constexpr int ib = CIDX[K0 + KK][1];
      constexpr int ic = CIDX[K0 + KK][2];
      // reference op order: 3.0*(s[a]+s[b]+s[c]) - sum, no FMA contraction.
      float s3 = (s[ia] + s[ib]) + s[ic];
      float cv = __fsub_rn(__fmul_rn(3.0f, s3), sum);
#pragma unroll
      for (int j = 0; j < FS; ++j) cnt[KK][j] += (cv > bv[KK][j]) ? 1u : 0u;
    }
    do_kernels<GK, K0, FS, PSEL, KK + 1>(s, sum, bv, cnt);
  }
}

template <int GK, int K0, int FS, int KK>
__device__ __forceinline__ void init_k(const float* __restrict__ biases,
                                       int colbase,
                                       float (&bv)[GK][FS], unsigned (&cnt)[GK][FS]) {
  if constexpr (KK < GK) {
    const int cb = colbase + (K0 + KK) * FS;  // block-uniform -> s_load
#pragma unroll
    for (int j = 0; j < FS; ++j) {
      bv[KK][j] = biases[cb + j];
      cnt[KK][j] = 0u;
    }
    init_k<GK, K0, FS, KK + 1>(biases, colbase, bv, cnt);
  }
}

template <int GK, int K0, int FS, int KK>
__device__ __forceinline__ void write_k(unsigned* __restrict__ outT, int colbase,
                                        int n, const unsigned (&cnt)[GK][FS]) {
  if constexpr (KK < GK) {
    const int cb = colbase + (K0 + KK) * FS;
#pragma unroll
    for (int j = 0; j < FS; ++j) {
      atomicAdd(&outT[(cb + j) * NS + n], cnt[KK][j]);  // coalesced per wave
    }
    write_k<GK, K0, FS, KK + 1>(outT, colbase, n, cnt);
  }
}

// One t-range segment. Unconditional loads from the padded array, single
// per-lane base xb, index (t + j*d)*NS. unroll 1: no live-range blowup.
template <int GK, int K0, int FS, int PSEL>
__device__ __forceinline__ void run_seg(int tlo, int thi, int d,
                                        const float* __restrict__ xb,
                                        const float (&bv)[GK][FS],
                                        unsigned (&cnt)[GK][FS]) {
#pragma unroll 1
  for (int t = tlo; t < thi; ++t) {
    float s[9];
#pragma unroll
    for (int j = 0; j < 9; ++j) s[j] = xb[(t + j * d) * NS];
    // sequential left-fold, matching reference reduce order (pad zeros included)
    float sum = s[0];
#pragma unroll
    for (int j = 1; j < 9; ++j) sum += s[j];
    do_kernels<GK, K0, FS, PSEL, 0>(s, sum, bv, cnt);
  }
}

template <int GK, int K0, int FS>
__device__ __forceinline__ void body(const float* __restrict__ xTp,
                                     const float* __restrict__ biases,
                                     unsigned* __restrict__ outT, int d, int par,
                                     int colbase, int ts) {
  const int n = (int)threadIdx.x;  // sample id (4 waves x 64 lanes)
  // per-lane base: row (ROW0 - 4d), sample n. Tap j at row offset (t + j*d).
  const float* xb = xTp + (ROW0 - 4 * d) * NS + n;

  float bv[GK][FS];
  unsigned cnt[GK][FS];
  init_k<GK, K0, FS, 0>(biases, colbase, bv, cnt);

  const int p = 4 * d;
  const int t0 = ts * TCH, t1 = t0 + TCH;
  // [0,p) and [L-p,L): padded-parity kernels only. [p,L-p): all kernels.
  const int aHi = imin(t1, p);
  const int bLo = imax(t0, p), bHi = imin(t1, LSER - p);
  const int cLo = imax(t0, LSER - p);

  if (par == 0) {
    run_seg<GK, K0, FS, 0>(t0, aHi, d, xb, bv, cnt);
  } else {
    run_seg<GK, K0, FS, 1>(t0, aHi, d, xb, bv, cnt);
  }
  run_seg<GK, K0, FS, -1>(bLo, bHi, d, xb, bv, cnt);
  if (par == 0) {
    run_seg<GK, K0, FS, 0>(cLo, t1, d, xb, bv, cnt);
  } else {
    run_seg<GK, K0, FS, 1>(cLo, t1, d, xb, bv, cnt);
  }

  write_k<GK, K0, FS, 0>(outT, colbase, n, cnt);
}

// recursive group dispatch: g is block-uniform; K0 = G*GK compile-time.
template <int GK, int FS, int G = 0>
__device__ __forceinline__ void disp(int g, const float* __restrict__ xTp,
                                     const float* __restrict__ biases,
                                     unsigned* __restrict__ outT, int d, int par,
                                     int colbase, int ts) {
  if constexpr (G < 84 / GK) {
    if (g == G) {
      body<GK, G * GK, FS>(xTp, biases, outT, d, par, colbase, ts);
    } else {
      disp<GK, FS, G + 1>(g, xTp, biases, outT, d, par, colbase, ts);
    }
  }
}

}  // namespace

// ---------------------------------------------------------------------------

__global__ __launch_bounds__(256) void mr_transpose(const float* __restrict__ x,
                                                    float* __restrict__ xTp) {
  __shared__ float tile[32][33];
  const int t0 = blockIdx.x << 5;
  const int n0 = blockIdx.y << 5;
  const int tx = threadIdx.x & 31, ty = threadIdx.x >> 5;  // 32 x 8
#pragma unroll
  for (int i = 0; i < 32; i += 8)
    tile[ty + i][tx] = x[(n0 + ty + i) * LSER + t0 + tx];
  __syncthreads();
#pragma unroll
  for (int i = 0; i < 32; i += 8)
    xTp[(ROW0 + t0 + ty + i) * NS + n0 + tx] = tile[tx][ty + i];
}

__global__ __launch_bounds__(256) void mr_main(const float* __restrict__ xTp,
                                               const float* __restrict__ biases,
                                               unsigned* __restrict__ outT) {
  const int bid = (int)blockIdx.x;  // ALL selectors blockIdx-only (wave-uniform)
  int di = 0;
#pragma unroll 1
  while (di < NDIL - 1 && bid >= c_BSTART[di + 1]) ++di;
  const int rel = bid - c_BSTART[di];
  const int g = rel >> 4;               // kernel group
  const int ts = rel & 15;              // t-slice 0..15
  const int d = c_DIL[di];
  const int colbase = c_FOFF[di];
  const int par = di & 1;

  if (di == 0) {
    disp<3, 19>(g, xTp, biases, outT, d, par, colbase, ts);        // A: F=19
  } else if (di == 1) {
    disp<4, 12>(g, xTp, biases, outT, d, par, colbase, ts);        // B: F=12
  } else if (di == 3) {
    disp<6, 8>(g, xTp, biases, outT, d, par, colbase, ts);         // C: F=8
  } else if (di >= 17) {
    disp<12, 3>(g, xTp, biases, outT, d, par, colbase, ts);        // E: F=3
  } else {
    disp<12, 4>(g, xTp, biases, outT, d, par, colbase, ts);        // D: F=4
  }
}

__global__ __launch_bounds__(256) void mr_finalize(const unsigned* __restrict__ outT,
                                                   float* __restrict__ out) {
  __shared__ unsigned tile[64][65];
  __shared__ float sscale[64];
  const int tb = (int)blockIdx.x;  // 628 = 157 col-tiles x 4 n-tiles
  const int ct = tb % 157, nt = tb / 157;
  const int c0 = ct << 6, n0 = nt << 6;
  const int tid = (int)threadIdx.x;

  if (tid < 64) {
    const int col = c0 + tid;
    float sc = 0.0f;
    if (col < NFEAT) {
      int di = 0;
      while (di < NDIL - 1 && col >= c_FOFF[di + 1]) ++di;
      const int rel = col - c_FOFF[di];
      const int f = c_F[di];
      const int k = rel / f;
      const int d = c_DIL[di];
      const bool padded = (((di + k) & 1) == 0);
      const int T = padded ? LSER : (LSER - 8 * d);
      sc = 1.0f / (float)T;
    }
    sscale[tid] = sc;
  }
#pragma unroll
  for (int i = 0; i < 16; ++i) {
    const int lin = tid + (i << 8);
    const int dc = lin >> 6, dn = lin & 63;
    const int col = c0 + dc;
    tile[dc][dn] = (col < NFEAT) ? outT[col * NS + n0 + dn] : 0u;
  }
  __syncthreads();
#pragma unroll
  for (int i = 0; i < 16; ++i) {
    const int lin = tid + (i << 8);
    const int dn = lin >> 6, dc = lin & 63;
    const int col = c0 + dc;
    if (col < NFEAT)
      out[(n0 + dn) * NFEAT + col] = (float)tile[dc][dn] * sscale[dc];
  }
}

extern "C" void kernel_launch(void* const* d_in, const int* in_sizes, int n_in,
                              void* d_out, int out_size, void* d_ws, size_t ws_size,
                              hipStream_t stream) {
  (void)in_sizes; (void)n_in; (void)out_size; (void)ws_size;
  const float* x = (const float*)d_in[0];        // (256, 1, 1024) f32
  const float* biases = (const float*)d_in[1];   // (9996,) f32
  float* out = (float*)d_out;                    // (256, 9996) f32

  float* xTp = (float*)d_ws;                                   // 2 MiB (2048x256 f32)
  unsigned* outT = (unsigned*)((char*)d_ws + (size_t)(PADROWS * NS * 4));

  // zero pad rows + counters in one memset (regions are contiguous)
  hipMemsetAsync(d_ws, 0,
                 (size_t)PADROWS * NS * 4 + (size_t)NFEAT * NS * sizeof(unsigned),
                 stream);
  hipLaunchKernelGGL(mr_transpose, dim3(32, 8), dim3(256), 0, stream, x, xTp);
  hipLaunchKernelGGL(mr_main, dim3(NBLK), dim3(256), 0, stream, xTp, biases, outT);
  hipLaunchKernelGGL(mr_finalize, dim3(628), dim3(256), 0, stream, outT, out);
}